// Round 1
// baseline (2106.585 us; speedup 1.0000x reference)
//
#include <hip/hip_runtime.h>
#include <hip/hip_bf16.h>
#include <cstdint>

#define B_ 2
#define T_ 2048
#define HID 2048
#define NH 6
#define DK 256
#define DV 512
#define KEY_DIM (NH*DK)   // 1536
#define VAL_DIM (NH*DV)   // 3072
#define EPS_ 1e-5f
#define SCALE_ 0.0625f
#define MT (B_*T_)        // 4096

typedef __attribute__((ext_vector_type(8))) short short8;
typedef __attribute__((ext_vector_type(4))) float floatx4;
typedef __attribute__((ext_vector_type(4))) unsigned int uint4v;

__device__ inline unsigned short f32_to_bf16(float f) {
    union { float f; unsigned int u; } v; v.f = f;
    unsigned int u = v.u;
    u += 0x7fffu + ((u >> 16) & 1u);
    return (unsigned short)(u >> 16);
}

__device__ inline float silu_f(float x) { return x / (1.f + expf(-x)); }

// ---------------- convert f32 -> bf16 (elementwise) ----------------
__global__ __launch_bounds__(256) void cvt_bf16_kernel(const float* __restrict__ in,
                                                       unsigned short* __restrict__ out, int n) {
    int i = (blockIdx.x * 256 + threadIdx.x) * 4;
    if (i >= n) return;
    float4 v = *reinterpret_cast<const float4*>(in + i);
    ushort4 o;
    o.x = f32_to_bf16(v.x); o.y = f32_to_bf16(v.y);
    o.z = f32_to_bf16(v.z); o.w = f32_to_bf16(v.w);
    *reinterpret_cast<ushort4*>(out + i) = o;
}

// ---------------- transpose + convert: in f32 [K][N] -> out bf16 [N][K] ----------------
__global__ __launch_bounds__(256) void transpose_cvt_kernel(const float* __restrict__ in,
                                                            unsigned short* __restrict__ out,
                                                            int K, int N) {
    __shared__ float tile[64][65];
    int k0 = blockIdx.x * 64, n0 = blockIdx.y * 64;
    int r = threadIdx.x >> 2, c0 = (threadIdx.x & 3) * 16;
    const float* src = in + (size_t)(k0 + r) * N + n0 + c0;
#pragma unroll
    for (int j = 0; j < 16; j += 4) {
        float4 v = *reinterpret_cast<const float4*>(src + j);
        tile[r][c0 + j + 0] = v.x; tile[r][c0 + j + 1] = v.y;
        tile[r][c0 + j + 2] = v.z; tile[r][c0 + j + 3] = v.w;
    }
    __syncthreads();
    int n = threadIdx.x >> 2, kc = (threadIdx.x & 3) * 16;
    unsigned short* dst = out + (size_t)(n0 + n) * K + k0 + kc;
#pragma unroll
    for (int j = 0; j < 16; j += 4) {
        ushort4 o;
        o.x = f32_to_bf16(tile[kc + j + 0][n]);
        o.y = f32_to_bf16(tile[kc + j + 1][n]);
        o.z = f32_to_bf16(tile[kc + j + 2][n]);
        o.w = f32_to_bf16(tile[kc + j + 3][n]);
        *reinterpret_cast<ushort4*>(dst + j) = o;
    }
}

// ---------------- bf16 MFMA GEMM: C[M,N] = A[M,K] @ B[K,N], B given as BT[N,K] ----------------
#define BM 128
#define BN 128
#define BK 32
#define LDS_S 40   // bf16 elems per LDS row (32 + 8 pad)

__global__ __launch_bounds__(256) void gemm_bf16_kernel(const unsigned short* __restrict__ A,
                                                        const unsigned short* __restrict__ BT,
                                                        float* __restrict__ C,
                                                        int M, int N, int K) {
    __shared__ __align__(16) unsigned short As[BM * LDS_S];
    __shared__ __align__(16) unsigned short Bs[BN * LDS_S];
    int tid = threadIdx.x;
    int m0 = blockIdx.y * BM, n0 = blockIdx.x * BN;
    int wave = tid >> 6, lane = tid & 63;
    int wr = (wave >> 1) * 64, wc = (wave & 1) * 64;
    int l15 = lane & 15, lh = lane >> 4;

    int srow = tid >> 1, shalf = tid & 1;
    const unsigned short* agp = A + (size_t)(m0 + srow) * K + shalf * 16;
    const unsigned short* bgp = BT + (size_t)(n0 + srow) * K + shalf * 16;
    unsigned short* asl = As + srow * LDS_S + shalf * 16;
    unsigned short* bsl = Bs + srow * LDS_S + shalf * 16;

    floatx4 acc[4][4];
#pragma unroll
    for (int m = 0; m < 4; m++)
#pragma unroll
        for (int n = 0; n < 4; n++) acc[m][n] = (floatx4){0.f, 0.f, 0.f, 0.f};

    for (int kt = 0; kt < K; kt += BK) {
        uint4v av0 = *reinterpret_cast<const uint4v*>(agp + kt);
        uint4v av1 = *reinterpret_cast<const uint4v*>(agp + kt + 8);
        uint4v bv0 = *reinterpret_cast<const uint4v*>(bgp + kt);
        uint4v bv1 = *reinterpret_cast<const uint4v*>(bgp + kt + 8);
        __syncthreads();
        *reinterpret_cast<uint4v*>(asl) = av0;
        *reinterpret_cast<uint4v*>(asl + 8) = av1;
        *reinterpret_cast<uint4v*>(bsl) = bv0;
        *reinterpret_cast<uint4v*>(bsl + 8) = bv1;
        __syncthreads();
        short8 a[4], b[4];
#pragma unroll
        for (int i = 0; i < 4; i++)
            a[i] = *reinterpret_cast<const short8*>(As + (wr + i * 16 + l15) * LDS_S + lh * 8);
#pragma unroll
        for (int i = 0; i < 4; i++)
            b[i] = *reinterpret_cast<const short8*>(Bs + (wc + i * 16 + l15) * LDS_S + lh * 8);
#pragma unroll
        for (int m = 0; m < 4; m++)
#pragma unroll
            for (int n = 0; n < 4; n++)
                acc[m][n] = __builtin_amdgcn_mfma_f32_16x16x32_bf16(a[m], b[n], acc[m][n], 0, 0, 0);
    }

#pragma unroll
    for (int m = 0; m < 4; m++)
#pragma unroll
        for (int n = 0; n < 4; n++) {
            int row = m0 + wr + m * 16 + lh * 4;
            int col = n0 + wc + n * 16 + l15;
#pragma unroll
            for (int j = 0; j < 4; j++)
                C[(size_t)(row + j) * N + col] = acc[m][n][j];
        }
}

// ---------------- a/b projections + softplus/sigmoid ----------------
__global__ __launch_bounds__(256) void ab_kernel(const float* __restrict__ x,
                                                 const float* __restrict__ wa,
                                                 const float* __restrict__ wb,
                                                 const float* __restrict__ A_log,
                                                 const float* __restrict__ dtb,
                                                 float* __restrict__ glog,
                                                 float* __restrict__ beta) {
    int bt = blockIdx.x, tid = threadIdx.x;
    const float* xr = x + (size_t)bt * HID;
    float pa[NH], pb[NH];
#pragma unroll
    for (int h = 0; h < NH; h++) { pa[h] = 0.f; pb[h] = 0.f; }
    for (int k = tid; k < HID; k += 256) {
        float xv = xr[k];
#pragma unroll
        for (int h = 0; h < NH; h++) {
            pa[h] = fmaf(xv, wa[k * NH + h], pa[h]);
            pb[h] = fmaf(xv, wb[k * NH + h], pb[h]);
        }
    }
    __shared__ float red[256][12];
#pragma unroll
    for (int h = 0; h < NH; h++) { red[tid][h] = pa[h]; red[tid][NH + h] = pb[h]; }
    __syncthreads();
    for (int s = 128; s > 0; s >>= 1) {
        if (tid < s)
#pragma unroll
            for (int j = 0; j < 12; j++) red[tid][j] += red[tid + s][j];
        __syncthreads();
    }
    if (tid < NH) {
        float a = red[0][tid] + dtb[tid];
        float sp = (a > 20.f) ? a : log1pf(expf(a));
        glog[(size_t)bt * NH + tid] = -expf(A_log[tid]) * sp;
        float bv = red[0][NH + tid];
        beta[(size_t)bt * NH + tid] = 1.f / (1.f + expf(-bv));
    }
}

// ---------------- causal conv(4) + SiLU + per-head l2norm (q,k) ----------------
__global__ __launch_bounds__(256) void conv_silu_l2norm_kernel(const float* __restrict__ in,
                                                               const float* __restrict__ w,
                                                               float* __restrict__ out) {
    int bt = blockIdx.x;
    int h = blockIdx.y;
    int t = bt & (T_ - 1);
    int c = h * DK + threadIdx.x;
    float4 wv = *reinterpret_cast<const float4*>(w + (size_t)c * 4);
    float acc = 0.f;
    if (t >= 3) {
        acc = in[(size_t)(bt - 3) * KEY_DIM + c] * wv.x
            + in[(size_t)(bt - 2) * KEY_DIM + c] * wv.y
            + in[(size_t)(bt - 1) * KEY_DIM + c] * wv.z
            + in[(size_t)(bt) * KEY_DIM + c] * wv.w;
    } else {
        if (t - 3 >= 0) acc = fmaf(in[(size_t)(bt - 3) * KEY_DIM + c], wv.x, acc);
        if (t - 2 >= 0) acc = fmaf(in[(size_t)(bt - 2) * KEY_DIM + c], wv.y, acc);
        if (t - 1 >= 0) acc = fmaf(in[(size_t)(bt - 1) * KEY_DIM + c], wv.z, acc);
        acc = fmaf(in[(size_t)bt * KEY_DIM + c], wv.w, acc);
    }
    float s = silu_f(acc);
    float ss = s * s;
#pragma unroll
    for (int m = 1; m < 64; m <<= 1) ss += __shfl_xor(ss, m);
    __shared__ float wsum[4];
    if ((threadIdx.x & 63) == 0) wsum[threadIdx.x >> 6] = ss;
    __syncthreads();
    float tot = wsum[0] + wsum[1] + wsum[2] + wsum[3];
    float r = 1.f / fmaxf(sqrtf(tot), 1e-6f);
    out[(size_t)bt * KEY_DIM + c] = s * r;
}

// ---------------- causal conv(4) + SiLU (v) ----------------
__global__ __launch_bounds__(256) void conv_silu_kernel(const float* __restrict__ in,
                                                        const float* __restrict__ w,
                                                        float* __restrict__ out) {
    int bt = blockIdx.x;
    int c = blockIdx.y * 256 + threadIdx.x;
    int t = bt & (T_ - 1);
    float4 wv = *reinterpret_cast<const float4*>(w + (size_t)c * 4);
    float acc = 0.f;
    if (t >= 3) {
        acc = in[(size_t)(bt - 3) * VAL_DIM + c] * wv.x
            + in[(size_t)(bt - 2) * VAL_DIM + c] * wv.y
            + in[(size_t)(bt - 1) * VAL_DIM + c] * wv.z
            + in[(size_t)(bt) * VAL_DIM + c] * wv.w;
    } else {
        if (t - 3 >= 0) acc = fmaf(in[(size_t)(bt - 3) * VAL_DIM + c], wv.x, acc);
        if (t - 2 >= 0) acc = fmaf(in[(size_t)(bt - 2) * VAL_DIM + c], wv.y, acc);
        if (t - 1 >= 0) acc = fmaf(in[(size_t)(bt - 1) * VAL_DIM + c], wv.z, acc);
        acc = fmaf(in[(size_t)bt * VAL_DIM + c], wv.w, acc);
    }
    out[(size_t)bt * VAL_DIM + c] = silu_f(acc);
}

// ---------------- gated delta-rule scan, column-parallel ----------------
// 16 lanes per DV-column (each lane owns 16 DK rows), 8 columns per 128-thread block.
#define TC 16
#define SC_COLS 8

__global__ __launch_bounds__(128) void scan_kernel(const float* __restrict__ qc,
                                                   const float* __restrict__ kc,
                                                   const float* __restrict__ vc,
                                                   const float* __restrict__ glog,
                                                   const float* __restrict__ beta,
                                                   float* __restrict__ o) {
    int bid = blockIdx.x;
    int cg = bid & 63;
    int bh = bid >> 6;
    int b = bh / NH, h = bh % NH;
    int colbase = cg * SC_COLS;
    int tid = threadIdx.x;
    int lane = tid & 15, colg = tid >> 4;

    __shared__ __align__(16) float kp[4 * TC * 68];
    __shared__ __align__(16) float qp[4 * TC * 68];
    __shared__ float v_s[TC * SC_COLS];
    __shared__ float g_s[TC], b_s[TC];

    float S[16];
#pragma unroll
    for (int j = 0; j < 16; j++) S[j] = 0.f;

    size_t base_bt = (size_t)b * T_;

    for (int t0 = 0; t0 < T_; t0 += TC) {
        __syncthreads();
        // stage k,q (plane-interleaved for conflict-free ds_read_b128)
        for (int e = tid * 4; e < TC * DK; e += 128 * 4) {
            int i = e >> 8;
            int dk = e & 255;
            int pc = (dk >> 2) & 3, pl = dk >> 4;
            int dst = (pc * TC + i) * 68 + pl * 4;
            size_t gsrc = (base_bt + t0 + i) * KEY_DIM + h * DK + dk;
            *reinterpret_cast<float4*>(kp + dst) = *reinterpret_cast<const float4*>(kc + gsrc);
            *reinterpret_cast<float4*>(qp + dst) = *reinterpret_cast<const float4*>(qc + gsrc);
        }
        {
            int i = tid >> 3, cc = tid & 7;
            v_s[tid] = vc[(base_bt + t0 + i) * VAL_DIM + h * DV + colbase + cc];
        }
        if (tid < TC) {
            g_s[tid] = glog[(base_bt + t0 + tid) * NH + h];
            b_s[tid] = beta[(base_bt + t0 + tid) * NH + h];
        }
        __syncthreads();

        for (int i = 0; i < TC; i++) {
            float d = __expf(g_s[i]);
            float bet = b_s[i];
            float vv = v_s[i * SC_COLS + colg];
            float kf[16], qf[16];
#pragma unroll
            for (int pc = 0; pc < 4; pc++) {
                *reinterpret_cast<float4*>(kf + pc * 4) =
                    *reinterpret_cast<const float4*>(kp + (pc * TC + i) * 68 + lane * 4);
                *reinterpret_cast<float4*>(qf + pc * 4) =
                    *reinterpret_cast<const float4*>(qp + (pc * TC + i) * 68 + lane * 4);
            }
            float cs = 0.f;
#pragma unroll
            for (int j = 0; j < 16; j++) cs = fmaf(kf[j], S[j], cs);
            cs += __shfl_xor(cs, 1); cs += __shfl_xor(cs, 2);
            cs += __shfl_xor(cs, 4); cs += __shfl_xor(cs, 8);
            float u = bet * (vv - d * cs);
            float os = 0.f;
#pragma unroll
            for (int j = 0; j < 16; j++) {
                S[j] = fmaf(d, S[j], kf[j] * u);
                os = fmaf(qf[j], S[j], os);
            }
            os += __shfl_xor(os, 1); os += __shfl_xor(os, 2);
            os += __shfl_xor(os, 4); os += __shfl_xor(os, 8);
            if (lane == 0)
                o[(base_bt + t0 + i) * VAL_DIM + h * DV + colbase + colg] = SCALE_ * os;
        }
    }
}

// ---------------- gated RMSNorm * w * silu(g) -> bf16 ----------------
__global__ __launch_bounds__(256) void gated_norm_kernel(const float* __restrict__ o,
                                                         const float* __restrict__ g,
                                                         const float* __restrict__ nw,
                                                         unsigned short* __restrict__ out) {
    int bt = blockIdx.x, h = blockIdx.y, tid = threadIdx.x;
    const float* orow = o + (size_t)bt * VAL_DIM + h * DV;
    const float* grow = g + (size_t)bt * VAL_DIM + h * DV;
    float x0 = orow[tid], x1 = orow[tid + 256];
    float ss = x0 * x0 + x1 * x1;
#pragma unroll
    for (int m = 1; m < 64; m <<= 1) ss += __shfl_xor(ss, m);
    __shared__ float wsum[4];
    if ((tid & 63) == 0) wsum[tid >> 6] = ss;
    __syncthreads();
    float tot = wsum[0] + wsum[1] + wsum[2] + wsum[3];
    float r = rsqrtf(tot / (float)DV + EPS_);
    float o0 = x0 * r * nw[tid] * silu_f(grow[tid]);
    float o1 = x1 * r * nw[tid + 256] * silu_f(grow[tid + 256]);
    unsigned short* orow_o = out + (size_t)bt * VAL_DIM + h * DV;
    orow_o[tid] = f32_to_bf16(o0);
    orow_o[tid + 256] = f32_to_bf16(o1);
}

extern "C" void kernel_launch(void* const* d_in, const int* in_sizes, int n_in,
                              void* d_out, int out_size, void* d_ws, size_t ws_size,
                              hipStream_t stream) {
    const float* x     = (const float*)d_in[0];
    const float* w_q   = (const float*)d_in[1];
    const float* w_k   = (const float*)d_in[2];
    const float* w_v   = (const float*)d_in[3];
    const float* w_a   = (const float*)d_in[4];
    const float* w_b   = (const float*)d_in[5];
    const float* w_g   = (const float*)d_in[6];
    const float* w_o   = (const float*)d_in[7];
    const float* cq    = (const float*)d_in[8];
    const float* ck    = (const float*)d_in[9];
    const float* cv    = (const float*)d_in[10];
    const float* A_log = (const float*)d_in[11];
    const float* dtb   = (const float*)d_in[12];
    const float* nw    = (const float*)d_in[13];
    float* out = (float*)d_out;

    char* ws = (char*)d_ws;
    size_t off = 0;
    auto alloc = [&](size_t bytes) {
        char* p = ws + off;
        off += (bytes + 255) & ~(size_t)255;
        return p;
    };
    unsigned short* xb = (unsigned short*)alloc((size_t)MT * HID * 2);
    unsigned short* wT = (unsigned short*)alloc((size_t)VAL_DIM * HID * 2);  // max transposed weight
    float* P1 = (float*)alloc((size_t)MT * KEY_DIM * 4);
    float* QC = (float*)alloc((size_t)MT * KEY_DIM * 4);
    float* KC = (float*)alloc((size_t)MT * KEY_DIM * 4);
    float* P2 = (float*)alloc((size_t)MT * VAL_DIM * 4);
    float* VC = (float*)alloc((size_t)MT * VAL_DIM * 4);
    float* OB = (float*)alloc((size_t)MT * VAL_DIM * 4);
    float* GL = (float*)alloc((size_t)MT * NH * 4);
    float* BE = (float*)alloc((size_t)MT * NH * 4);
    unsigned short* ONB = (unsigned short*)P1;  // reuse P1 (free after conv_k)

    // x -> bf16
    cvt_bf16_kernel<<<(MT * HID) / 1024, 256, 0, stream>>>(x, xb, MT * HID);

    // q path
    transpose_cvt_kernel<<<dim3(HID / 64, KEY_DIM / 64), 256, 0, stream>>>(w_q, wT, HID, KEY_DIM);
    gemm_bf16_kernel<<<dim3(KEY_DIM / BN, MT / BM), 256, 0, stream>>>(xb, wT, P1, MT, KEY_DIM, HID);
    conv_silu_l2norm_kernel<<<dim3(MT, NH), 256, 0, stream>>>(P1, cq, QC);

    // k path
    transpose_cvt_kernel<<<dim3(HID / 64, KEY_DIM / 64), 256, 0, stream>>>(w_k, wT, HID, KEY_DIM);
    gemm_bf16_kernel<<<dim3(KEY_DIM / BN, MT / BM), 256, 0, stream>>>(xb, wT, P1, MT, KEY_DIM, HID);
    conv_silu_l2norm_kernel<<<dim3(MT, NH), 256, 0, stream>>>(P1, ck, KC);

    // v path
    transpose_cvt_kernel<<<dim3(HID / 64, VAL_DIM / 64), 256, 0, stream>>>(w_v, wT, HID, VAL_DIM);
    gemm_bf16_kernel<<<dim3(VAL_DIM / BN, MT / BM), 256, 0, stream>>>(xb, wT, P2, MT, VAL_DIM, HID);
    conv_silu_kernel<<<dim3(MT, VAL_DIM / 256), 256, 0, stream>>>(P2, cv, VC);

    // g path (reuses P2 after conv_v consumed it)
    transpose_cvt_kernel<<<dim3(HID / 64, VAL_DIM / 64), 256, 0, stream>>>(w_g, wT, HID, VAL_DIM);
    gemm_bf16_kernel<<<dim3(VAL_DIM / BN, MT / BM), 256, 0, stream>>>(xb, wT, P2, MT, VAL_DIM, HID);

    // a/b projections (f32, exact)
    ab_kernel<<<MT, 256, 0, stream>>>(x, w_a, w_b, A_log, dtb, GL, BE);

    // recurrent scan
    scan_kernel<<<B_ * NH * (DV / SC_COLS), 128, 0, stream>>>(QC, KC, VC, GL, BE, OB);

    // gated RMSNorm -> bf16
    gated_norm_kernel<<<dim3(MT, NH), 256, 0, stream>>>(OB, P2, nw, ONB);

    // output projection
    transpose_cvt_kernel<<<dim3(VAL_DIM / 64, HID / 64), 256, 0, stream>>>(w_o, wT, VAL_DIM, HID);
    gemm_bf16_kernel<<<dim3(HID / BN, MT / BM), 256, 0, stream>>>(ONB, wT, out, MT, HID, VAL_DIM);
}

// Round 3
// 1143.385 us; speedup vs baseline: 1.8424x; 1.8424x over previous
//
#include <hip/hip_runtime.h>
#include <hip/hip_bf16.h>
#include <cstdint>

#define B_ 2
#define T_ 2048
#define HID 2048
#define NH 6
#define DK 256
#define DV 512
#define KEY_DIM (NH*DK)   // 1536
#define VAL_DIM (NH*DV)   // 3072
#define EPS_ 1e-5f
#define SCALE_ 0.0625f
#define MT (B_*T_)        // 4096
#define CC 64             // chunk length
#define NC (T_/CC)        // 32 chunks per batch row

typedef __attribute__((ext_vector_type(8))) short short8;
typedef __attribute__((ext_vector_type(4))) float floatx4;
typedef __attribute__((ext_vector_type(4))) unsigned int uint4v;

union Pk8 { unsigned short us[8]; uint4v v; };

__device__ inline unsigned short f32_to_bf16(float f) {
    union { float f; unsigned int u; } v; v.f = f;
    unsigned int u = v.u;
    u += 0x7fffu + ((u >> 16) & 1u);
    return (unsigned short)(u >> 16);
}

__device__ inline float bf16_to_f32(unsigned short u) {
    union { unsigned int u; float f; } v; v.u = ((unsigned int)u) << 16;
    return v.f;
}

__device__ inline float silu_f(float x) { return x / (1.f + expf(-x)); }

// ---------------- convert f32 -> bf16 (elementwise) ----------------
__global__ __launch_bounds__(256) void cvt_bf16_kernel(const float* __restrict__ in,
                                                       unsigned short* __restrict__ out, int n) {
    int i = (blockIdx.x * 256 + threadIdx.x) * 4;
    if (i >= n) return;
    float4 v = *reinterpret_cast<const float4*>(in + i);
    ushort4 o;
    o.x = f32_to_bf16(v.x); o.y = f32_to_bf16(v.y);
    o.z = f32_to_bf16(v.z); o.w = f32_to_bf16(v.w);
    *reinterpret_cast<ushort4*>(out + i) = o;
}

// ---------------- transpose + convert: in f32 [K][N] -> out bf16 [N][K] ----------------
__global__ __launch_bounds__(256) void transpose_cvt_kernel(const float* __restrict__ in,
                                                            unsigned short* __restrict__ out,
                                                            int K, int N) {
    __shared__ float tile[64][65];
    int k0 = blockIdx.x * 64, n0 = blockIdx.y * 64;
    int r = threadIdx.x >> 2, c0 = (threadIdx.x & 3) * 16;
    const float* src = in + (size_t)(k0 + r) * N + n0 + c0;
#pragma unroll
    for (int j = 0; j < 16; j += 4) {
        float4 v = *reinterpret_cast<const float4*>(src + j);
        tile[r][c0 + j + 0] = v.x; tile[r][c0 + j + 1] = v.y;
        tile[r][c0 + j + 2] = v.z; tile[r][c0 + j + 3] = v.w;
    }
    __syncthreads();
    int n = threadIdx.x >> 2, kc = (threadIdx.x & 3) * 16;
    unsigned short* dst = out + (size_t)(n0 + n) * K + k0 + kc;
#pragma unroll
    for (int j = 0; j < 16; j += 4) {
        ushort4 o;
        o.x = f32_to_bf16(tile[kc + j + 0][n]);
        o.y = f32_to_bf16(tile[kc + j + 1][n]);
        o.z = f32_to_bf16(tile[kc + j + 2][n]);
        o.w = f32_to_bf16(tile[kc + j + 3][n]);
        *reinterpret_cast<ushort4*>(dst + j) = o;
    }
}

// ---------------- bf16 MFMA GEMM: C[M,N] = A[M,K] @ B[K,N], B given as BT[N,K] ----------------
#define BM 128
#define BN 128
#define BK 32
#define LDS_S 40   // bf16 elems per LDS row (32 + 8 pad)

__global__ __launch_bounds__(256) void gemm_bf16_kernel(const unsigned short* __restrict__ A,
                                                        const unsigned short* __restrict__ BT,
                                                        float* __restrict__ C,
                                                        int M, int N, int K) {
    __shared__ __align__(16) unsigned short As[BM * LDS_S];
    __shared__ __align__(16) unsigned short Bs[BN * LDS_S];
    int tid = threadIdx.x;
    int m0 = blockIdx.y * BM, n0 = blockIdx.x * BN;
    int wave = tid >> 6, lane = tid & 63;
    int wr = (wave >> 1) * 64, wc = (wave & 1) * 64;
    int l15 = lane & 15, lh = lane >> 4;

    int srow = tid >> 1, shalf = tid & 1;
    const unsigned short* agp = A + (size_t)(m0 + srow) * K + shalf * 16;
    const unsigned short* bgp = BT + (size_t)(n0 + srow) * K + shalf * 16;
    unsigned short* asl = As + srow * LDS_S + shalf * 16;
    unsigned short* bsl = Bs + srow * LDS_S + shalf * 16;

    floatx4 acc[4][4];
#pragma unroll
    for (int m = 0; m < 4; m++)
#pragma unroll
        for (int n = 0; n < 4; n++) acc[m][n] = (floatx4){0.f, 0.f, 0.f, 0.f};

    for (int kt = 0; kt < K; kt += BK) {
        uint4v av0 = *reinterpret_cast<const uint4v*>(agp + kt);
        uint4v av1 = *reinterpret_cast<const uint4v*>(agp + kt + 8);
        uint4v bv0 = *reinterpret_cast<const uint4v*>(bgp + kt);
        uint4v bv1 = *reinterpret_cast<const uint4v*>(bgp + kt + 8);
        __syncthreads();
        *reinterpret_cast<uint4v*>(asl) = av0;
        *reinterpret_cast<uint4v*>(asl + 8) = av1;
        *reinterpret_cast<uint4v*>(bsl) = bv0;
        *reinterpret_cast<uint4v*>(bsl + 8) = bv1;
        __syncthreads();
        short8 a[4], b[4];
#pragma unroll
        for (int i = 0; i < 4; i++)
            a[i] = *reinterpret_cast<const short8*>(As + (wr + i * 16 + l15) * LDS_S + lh * 8);
#pragma unroll
        for (int i = 0; i < 4; i++)
            b[i] = *reinterpret_cast<const short8*>(Bs + (wc + i * 16 + l15) * LDS_S + lh * 8);
#pragma unroll
        for (int m = 0; m < 4; m++)
#pragma unroll
            for (int n = 0; n < 4; n++)
                acc[m][n] = __builtin_amdgcn_mfma_f32_16x16x32_bf16(a[m], b[n], acc[m][n], 0, 0, 0);
    }

#pragma unroll
    for (int m = 0; m < 4; m++)
#pragma unroll
        for (int n = 0; n < 4; n++) {
            int row = m0 + wr + m * 16 + lh * 4;
            int col = n0 + wc + n * 16 + l15;
#pragma unroll
            for (int j = 0; j < 4; j++)
                C[(size_t)(row + j) * N + col] = acc[m][n][j];
        }
}

// ---------------- a/b projections + softplus/sigmoid ----------------
__global__ __launch_bounds__(256) void ab_kernel(const float* __restrict__ x,
                                                 const float* __restrict__ wa,
                                                 const float* __restrict__ wb,
                                                 const float* __restrict__ A_log,
                                                 const float* __restrict__ dtb,
                                                 float* __restrict__ glog,
                                                 float* __restrict__ beta) {
    int bt = blockIdx.x, tid = threadIdx.x;
    const float* xr = x + (size_t)bt * HID;
    float pa[NH], pb[NH];
#pragma unroll
    for (int h = 0; h < NH; h++) { pa[h] = 0.f; pb[h] = 0.f; }
    for (int k = tid; k < HID; k += 256) {
        float xv = xr[k];
#pragma unroll
        for (int h = 0; h < NH; h++) {
            pa[h] = fmaf(xv, wa[k * NH + h], pa[h]);
            pb[h] = fmaf(xv, wb[k * NH + h], pb[h]);
        }
    }
    __shared__ float red[256][12];
#pragma unroll
    for (int h = 0; h < NH; h++) { red[tid][h] = pa[h]; red[tid][NH + h] = pb[h]; }
    __syncthreads();
    for (int s = 128; s > 0; s >>= 1) {
        if (tid < s)
#pragma unroll
            for (int j = 0; j < 12; j++) red[tid][j] += red[tid + s][j];
        __syncthreads();
    }
    if (tid < NH) {
        float a = red[0][tid] + dtb[tid];
        float sp = (a > 20.f) ? a : log1pf(expf(a));
        glog[(size_t)bt * NH + tid] = -expf(A_log[tid]) * sp;
        float bv = red[0][NH + tid];
        beta[(size_t)bt * NH + tid] = 1.f / (1.f + expf(-bv));
    }
}

// ---------------- causal conv(4) + SiLU + per-head l2norm (q,k) ----------------
__global__ __launch_bounds__(256) void conv_silu_l2norm_kernel(const float* __restrict__ in,
                                                               const float* __restrict__ w,
                                                               float* __restrict__ out) {
    int bt = blockIdx.x;
    int h = blockIdx.y;
    int t = bt & (T_ - 1);
    int c = h * DK + threadIdx.x;
    float4 wv = *reinterpret_cast<const float4*>(w + (size_t)c * 4);
    float acc = 0.f;
    if (t >= 3) {
        acc = in[(size_t)(bt - 3) * KEY_DIM + c] * wv.x
            + in[(size_t)(bt - 2) * KEY_DIM + c] * wv.y
            + in[(size_t)(bt - 1) * KEY_DIM + c] * wv.z
            + in[(size_t)(bt) * KEY_DIM + c] * wv.w;
    } else {
        if (t - 3 >= 0) acc = fmaf(in[(size_t)(bt - 3) * KEY_DIM + c], wv.x, acc);
        if (t - 2 >= 0) acc = fmaf(in[(size_t)(bt - 2) * KEY_DIM + c], wv.y, acc);
        if (t - 1 >= 0) acc = fmaf(in[(size_t)(bt - 1) * KEY_DIM + c], wv.z, acc);
        acc = fmaf(in[(size_t)bt * KEY_DIM + c], wv.w, acc);
    }
    float s = silu_f(acc);
    float ss = s * s;
#pragma unroll
    for (int m = 1; m < 64; m <<= 1) ss += __shfl_xor(ss, m);
    __shared__ float wsum[4];
    if ((threadIdx.x & 63) == 0) wsum[threadIdx.x >> 6] = ss;
    __syncthreads();
    float tot = wsum[0] + wsum[1] + wsum[2] + wsum[3];
    float r = 1.f / fmaxf(sqrtf(tot), 1e-6f);
    out[(size_t)bt * KEY_DIM + c] = s * r;
}

// ---------------- causal conv(4) + SiLU (v) ----------------
__global__ __launch_bounds__(256) void conv_silu_kernel(const float* __restrict__ in,
                                                        const float* __restrict__ w,
                                                        float* __restrict__ out) {
    int bt = blockIdx.x;
    int c = blockIdx.y * 256 + threadIdx.x;
    int t = bt & (T_ - 1);
    float4 wv = *reinterpret_cast<const float4*>(w + (size_t)c * 4);
    float acc = 0.f;
    if (t >= 3) {
        acc = in[(size_t)(bt - 3) * VAL_DIM + c] * wv.x
            + in[(size_t)(bt - 2) * VAL_DIM + c] * wv.y
            + in[(size_t)(bt - 1) * VAL_DIM + c] * wv.z
            + in[(size_t)(bt) * VAL_DIM + c] * wv.w;
    } else {
        if (t - 3 >= 0) acc = fmaf(in[(size_t)(bt - 3) * VAL_DIM + c], wv.x, acc);
        if (t - 2 >= 0) acc = fmaf(in[(size_t)(bt - 2) * VAL_DIM + c], wv.y, acc);
        if (t - 1 >= 0) acc = fmaf(in[(size_t)(bt - 1) * VAL_DIM + c], wv.z, acc);
        acc = fmaf(in[(size_t)bt * VAL_DIM + c], wv.w, acc);
    }
    out[(size_t)bt * VAL_DIM + c] = silu_f(acc);
}

// ================= chunked gated delta rule =================
// Pass 1 (chunk-parallel): per (bh, chunk): decays, KK^T/QK^T (MFMA), M,
// T = (I+M)^-1 (forward substitution), pre-scaled bf16 operands.
// Layouts per chunk idx = bh*NC + c:
//   Qg  [64][256] bf16 : SCALE*gamma_t*q_t            (A/B operand, t-major, k-contig)
//   KB  [64][256] bf16 : b_t*gamma_t*k_t
//   KlT [256][64] bf16 : (gammaEnd/gamma_s)*k_s, dk-major
//   Tm  [64][64]  bf16 : (I+M)^-1, [t][s]
//   Am  [64][64]  bf16 : SCALE*exp(G_t-G_s)*(q_t.k_s) for s<=t else 0, [t][s]
//   BVT [512][64] bf16 : b_c*v_c, dv-major
//   gend[1] f32        : gammaEnd
__global__ __launch_bounds__(256, 1) void chunk_prep_kernel(
    const float* __restrict__ QC, const float* __restrict__ KC, const float* __restrict__ VC,
    const float* __restrict__ GL, const float* __restrict__ BE,
    unsigned short* __restrict__ Qg, unsigned short* __restrict__ KB,
    unsigned short* __restrict__ KlT, unsigned short* __restrict__ Tm,
    unsigned short* __restrict__ Am, unsigned short* __restrict__ BVT,
    float* __restrict__ gend) {
    int c = blockIdx.x;       // chunk within batch-row
    int bh = blockIdx.y;      // b*NH + h
    int b = bh / NH, h = bh % NH;
    size_t idx = (size_t)bh * NC + c;
    int bt0 = b * T_ + c * CC;

    __shared__ __align__(16) char ldsbuf[64 * 264 * 2 * 2];  // Kb | Qb ; reused as Vst f32
    unsigned short* Kb = (unsigned short*)ldsbuf;
    unsigned short* Qb = (unsigned short*)(ldsbuf + 64 * 264 * 2);
    float* Vst = (float*)ldsbuf;     // [64][264] f32 overlays Kb+Qb
    __shared__ float Ms[64 * 65];
    __shared__ float Ts[64 * 65];
    __shared__ float gc[64], es[64], bb_s[64], gtmp[64];

    int tid = threadIdx.x, wave = tid >> 6, lane = tid & 63;
    int l15 = lane & 15, lh = lane >> 4;

    if (tid < 64) {
        gtmp[tid] = GL[(size_t)(bt0 + tid) * NH + h];
        bb_s[tid] = BE[(size_t)(bt0 + tid) * NH + h];
    }

    // stage K, Q chunk as bf16 [64][264]
    {
        int r = tid >> 2, seg = (tid & 3) * 64;
        const float* ksrc = KC + (size_t)(bt0 + r) * KEY_DIM + h * DK + seg;
        const float* qsrc = QC + (size_t)(bt0 + r) * KEY_DIM + h * DK + seg;
#pragma unroll
        for (int jj = 0; jj < 8; jj++) {
            float4 a = *reinterpret_cast<const float4*>(ksrc + jj * 8);
            float4 a2 = *reinterpret_cast<const float4*>(ksrc + jj * 8 + 4);
            Pk8 pk;
            pk.us[0] = f32_to_bf16(a.x);  pk.us[1] = f32_to_bf16(a.y);
            pk.us[2] = f32_to_bf16(a.z);  pk.us[3] = f32_to_bf16(a.w);
            pk.us[4] = f32_to_bf16(a2.x); pk.us[5] = f32_to_bf16(a2.y);
            pk.us[6] = f32_to_bf16(a2.z); pk.us[7] = f32_to_bf16(a2.w);
            *reinterpret_cast<uint4v*>(Kb + r * 264 + seg + jj * 8) = pk.v;
            float4 qa = *reinterpret_cast<const float4*>(qsrc + jj * 8);
            float4 qa2 = *reinterpret_cast<const float4*>(qsrc + jj * 8 + 4);
            pk.us[0] = f32_to_bf16(qa.x);  pk.us[1] = f32_to_bf16(qa.y);
            pk.us[2] = f32_to_bf16(qa.z);  pk.us[3] = f32_to_bf16(qa.w);
            pk.us[4] = f32_to_bf16(qa2.x); pk.us[5] = f32_to_bf16(qa2.y);
            pk.us[6] = f32_to_bf16(qa2.z); pk.us[7] = f32_to_bf16(qa2.w);
            *reinterpret_cast<uint4v*>(Qb + r * 264 + seg + jj * 8) = pk.v;
        }
    }
    __syncthreads();
    if (tid == 0) {
        float a = 0.f;
#pragma unroll
        for (int t = 0; t < 64; t++) { a += gtmp[t]; gc[t] = a; }
    }
    __syncthreads();
    if (tid < 64) es[tid] = __expf(gc[63] - gc[tid]);

    // KK^T and QK^T via MFMA (wave w owns t-rows 16w..16w+15)
    floatx4 kkf[4], qkf[4];
#pragma unroll
    for (int nt = 0; nt < 4; nt++) { kkf[nt] = (floatx4){0,0,0,0}; qkf[nt] = (floatx4){0,0,0,0}; }
#pragma unroll
    for (int kk = 0; kk < 8; kk++) {
        short8 ak = *reinterpret_cast<const short8*>(Kb + (wave * 16 + l15) * 264 + kk * 32 + lh * 8);
        short8 aq = *reinterpret_cast<const short8*>(Qb + (wave * 16 + l15) * 264 + kk * 32 + lh * 8);
#pragma unroll
        for (int nt = 0; nt < 4; nt++) {
            short8 bk = *reinterpret_cast<const short8*>(Kb + (nt * 16 + l15) * 264 + kk * 32 + lh * 8);
            kkf[nt] = __builtin_amdgcn_mfma_f32_16x16x32_bf16(ak, bk, kkf[nt], 0, 0, 0);
            qkf[nt] = __builtin_amdgcn_mfma_f32_16x16x32_bf16(aq, bk, qkf[nt], 0, 0, 0);
        }
    }
    // M (LDS) and A (global bf16)
#pragma unroll
    for (int nt = 0; nt < 4; nt++)
#pragma unroll
        for (int j = 0; j < 4; j++) {
            int t = wave * 16 + lh * 4 + j;
            int s = nt * 16 + l15;
            float dec = (s <= t) ? __expf(gc[t] - gc[s]) : 0.f;
            Ms[t * 65 + s] = (s < t) ? bb_s[t] * dec * kkf[nt][j] : 0.f;
            float av = (s <= t) ? SCALE_ * dec * qkf[nt][j] : 0.f;
            Am[idx * 4096 + t * 64 + s] = f32_to_bf16(av);
        }
    __syncthreads();

    // T = (I+M)^-1 by forward substitution; thread j owns column j
    if (tid < 64) {
        int j = tid;
        for (int t = 0; t < 64; t++) {
            if (t < j) Ts[t * 65 + j] = 0.f;
            else if (t == j) Ts[t * 65 + j] = 1.f;
            else {
                float sum = 0.f;
                for (int s = j; s < t; s++) sum += Ms[t * 65 + s] * Ts[s * 65 + j];
                Ts[t * 65 + j] = -sum;
            }
        }
    }
    __syncthreads();

    // store T (bf16, coalesced)
    {
        int rr = tid >> 2, sseg = (tid & 3) * 16;
#pragma unroll
        for (int g2 = 0; g2 < 2; g2++) {
            Pk8 pk;
#pragma unroll
            for (int e = 0; e < 8; e++) pk.us[e] = f32_to_bf16(Ts[rr * 65 + sseg + g2 * 8 + e]);
            *reinterpret_cast<uint4v*>(Tm + idx * 4096 + rr * 64 + sseg + g2 * 8) = pk.v;
        }
    }
    // Qg = SCALE*gamma_t*q ; KB = b_t*gamma_t*k
    {
        int r = tid >> 2, seg = (tid & 3) * 64;
        float gmm = __expf(gc[r]);
        float qs = SCALE_ * gmm, ksc = bb_s[r] * gmm;
        const float* qsrc = QC + (size_t)(bt0 + r) * KEY_DIM + h * DK + seg;
        const float* ksrc = KC + (size_t)(bt0 + r) * KEY_DIM + h * DK + seg;
#pragma unroll
        for (int jj = 0; jj < 8; jj++) {
            float4 a = *reinterpret_cast<const float4*>(qsrc + jj * 8);
            float4 a2 = *reinterpret_cast<const float4*>(qsrc + jj * 8 + 4);
            Pk8 pk;
            pk.us[0] = f32_to_bf16(a.x * qs);  pk.us[1] = f32_to_bf16(a.y * qs);
            pk.us[2] = f32_to_bf16(a.z * qs);  pk.us[3] = f32_to_bf16(a.w * qs);
            pk.us[4] = f32_to_bf16(a2.x * qs); pk.us[5] = f32_to_bf16(a2.y * qs);
            pk.us[6] = f32_to_bf16(a2.z * qs); pk.us[7] = f32_to_bf16(a2.w * qs);
            *reinterpret_cast<uint4v*>(Qg + idx * 16384 + r * 256 + seg + jj * 8) = pk.v;
            float4 ka = *reinterpret_cast<const float4*>(ksrc + jj * 8);
            float4 ka2 = *reinterpret_cast<const float4*>(ksrc + jj * 8 + 4);
            pk.us[0] = f32_to_bf16(ka.x * ksc);  pk.us[1] = f32_to_bf16(ka.y * ksc);
            pk.us[2] = f32_to_bf16(ka.z * ksc);  pk.us[3] = f32_to_bf16(ka.w * ksc);
            pk.us[4] = f32_to_bf16(ka2.x * ksc); pk.us[5] = f32_to_bf16(ka2.y * ksc);
            pk.us[6] = f32_to_bf16(ka2.z * ksc); pk.us[7] = f32_to_bf16(ka2.w * ksc);
            *reinterpret_cast<uint4v*>(KB + idx * 16384 + r * 256 + seg + jj * 8) = pk.v;
        }
    }
    // KlT[dk][s] = k_s[dk] * (gammaEnd/gamma_s)
    {
        int dk = tid;
#pragma unroll
        for (int sb = 0; sb < 8; sb++) {
            Pk8 pk;
#pragma unroll
            for (int e = 0; e < 8; e++) {
                int s = sb * 8 + e;
                pk.us[e] = f32_to_bf16(bf16_to_f32(Kb[s * 264 + dk]) * es[s]);
            }
            *reinterpret_cast<uint4v*>(KlT + idx * 16384 + dk * 64 + sb * 8) = pk.v;
        }
    }
    // BVT[dv][c] = b_c * v_c[dv] (transpose through LDS, two halves)
    for (int hv = 0; hv < 2; hv++) {
        __syncthreads();  // prior Kb readers done / prev half done
        int r = tid >> 2, seg = (tid & 3) * 64;
        const float* vsrc = VC + (size_t)(bt0 + r) * VAL_DIM + h * DV + hv * 256 + seg;
#pragma unroll
        for (int jj = 0; jj < 16; jj++)
            *reinterpret_cast<float4*>(Vst + r * 264 + seg + jj * 4) =
                *reinterpret_cast<const float4*>(vsrc + jj * 4);
        __syncthreads();
#pragma unroll
        for (int sb = 0; sb < 8; sb++) {
            Pk8 pk;
#pragma unroll
            for (int e = 0; e < 8; e++) {
                int s = sb * 8 + e;
                pk.us[e] = f32_to_bf16(Vst[s * 264 + tid] * bb_s[s]);
            }
            *reinterpret_cast<uint4v*>(BVT + idx * 32768 + (size_t)(hv * 256 + tid) * 64 + sb * 8) = pk.v;
        }
    }
    if (tid == 0) gend[idx] = __expf(gc[63]);
}

// Pass 2: sequential over chunks; block = (dv-slice of 32, bh). State S^T [32][256]
// kept in f32 MFMA accumulators across chunks; bf16 shadow in LDS for operands.
__global__ __launch_bounds__(256, 1) void chunk_scan_kernel(
    const unsigned short* __restrict__ Qg, const unsigned short* __restrict__ KBp,
    const unsigned short* __restrict__ KlTp, const unsigned short* __restrict__ Tmp_,
    const unsigned short* __restrict__ Amp_, const unsigned short* __restrict__ BVTp,
    const float* __restrict__ gendp, float* __restrict__ O) {
    int slice = blockIdx.x;   // 0..15
    int bh = blockIdx.y;      // 0..11
    int b = bh / NH, h = bh % NH;
    int dvbase = slice * 32;
    int tid = threadIdx.x, wave = tid >> 6, lane = tid & 63;
    int l15 = lane & 15, lh = lane >> 4;
    int ms = wave >> 1;       // dv row strip (16 rows)
    int ns = wave & 1;        // column half

    __shared__ __align__(16) unsigned short QgB[64 * 264];
    __shared__ __align__(16) unsigned short KBB[64 * 264];
    __shared__ __align__(16) unsigned short KlTB[256 * 72];
    __shared__ __align__(16) unsigned short SbT[32 * 264];
    __shared__ __align__(16) unsigned short Wb[32 * 72];
    __shared__ __align__(16) unsigned short Ub[32 * 72];
    __shared__ __align__(16) float Ost[64 * 40];

    floatx4 st[8];
#pragma unroll
    for (int i = 0; i < 8; i++) st[i] = (floatx4){0.f, 0.f, 0.f, 0.f};
    for (int i = tid; i < 32 * 264; i += 256) SbT[i] = 0;

    int r = tid >> 2, seg = (tid & 3) * 64;

    for (int c = 0; c < NC; c++) {
        size_t idx = (size_t)bh * NC + c;
        const unsigned short* qg = Qg + idx * 16384;
        const unsigned short* kb = KBp + idx * 16384;
        const unsigned short* kl = KlTp + idx * 16384;
        const unsigned short* tm = Tmp_ + idx * 4096;
        const unsigned short* am = Amp_ + idx * 4096;
        const unsigned short* bvt = BVTp + idx * 32768;

        // -------- prefetch (registers) --------
        float ge = gendp[idx];
        short8 tfr[2][2], afr[2][2];
#pragma unroll
        for (int nt = 0; nt < 2; nt++)
#pragma unroll
            for (int kk = 0; kk < 2; kk++) {
                int tcol = ns * 32 + nt * 16 + l15;
                tfr[nt][kk] = *reinterpret_cast<const short8*>(tm + tcol * 64 + kk * 32 + lh * 8);
                afr[nt][kk] = *reinterpret_cast<const short8*>(am + tcol * 64 + kk * 32 + lh * 8);
            }
        float bvv[2][4];
#pragma unroll
        for (int nt = 0; nt < 2; nt++)
#pragma unroll
            for (int j = 0; j < 4; j++)
                bvv[nt][j] = bf16_to_f32(bvt[(size_t)(dvbase + ms * 16 + lh * 4 + j) * 64
                                             + ns * 32 + nt * 16 + l15]);
        uint4v qv[8], kv[8], klv[8];
#pragma unroll
        for (int j = 0; j < 8; j++) {
            qv[j] = *reinterpret_cast<const uint4v*>(qg + r * 256 + seg + j * 8);
            kv[j] = *reinterpret_cast<const uint4v*>(kb + r * 256 + seg + j * 8);
        }
#pragma unroll
        for (int j = 0; j < 8; j++)
            klv[j] = *reinterpret_cast<const uint4v*>(kl + tid * 64 + j * 8);

        __syncthreads();   // all waves done with previous chunk's buffers
#pragma unroll
        for (int j = 0; j < 8; j++) {
            *reinterpret_cast<uint4v*>(QgB + r * 264 + seg + j * 8) = qv[j];
            *reinterpret_cast<uint4v*>(KBB + r * 264 + seg + j * 8) = kv[j];
        }
#pragma unroll
        for (int j = 0; j < 8; j++)
            *reinterpret_cast<uint4v*>(KlTB + tid * 72 + j * 8) = klv[j];
        __syncthreads();

        // -------- X2 = Sb^T*Qg , X1 = Sb^T*KB --------
        floatx4 x2f[2], x1f[2];
#pragma unroll
        for (int nt = 0; nt < 2; nt++) { x2f[nt] = (floatx4){0,0,0,0}; x1f[nt] = (floatx4){0,0,0,0}; }
#pragma unroll
        for (int kk = 0; kk < 8; kk++) {
            short8 af = *reinterpret_cast<const short8*>(SbT + (ms * 16 + l15) * 264 + kk * 32 + lh * 8);
#pragma unroll
            for (int nt = 0; nt < 2; nt++) {
                short8 bq = *reinterpret_cast<const short8*>(QgB + (ns * 32 + nt * 16 + l15) * 264 + kk * 32 + lh * 8);
                short8 bk = *reinterpret_cast<const short8*>(KBB + (ns * 32 + nt * 16 + l15) * 264 + kk * 32 + lh * 8);
                x2f[nt] = __builtin_amdgcn_mfma_f32_16x16x32_bf16(af, bq, x2f[nt], 0, 0, 0);
                x1f[nt] = __builtin_amdgcn_mfma_f32_16x16x32_bf16(af, bk, x1f[nt], 0, 0, 0);
            }
        }
        // W = BV - X1  -> bf16 LDS
#pragma unroll
        for (int nt = 0; nt < 2; nt++)
#pragma unroll
            for (int j = 0; j < 4; j++)
                Wb[(ms * 16 + lh * 4 + j) * 72 + ns * 32 + nt * 16 + l15] =
                    f32_to_bf16(bvv[nt][j] - x1f[nt][j]);
        __syncthreads();

        // -------- U = W * T --------
        floatx4 uf[2];
#pragma unroll
        for (int nt = 0; nt < 2; nt++) uf[nt] = (floatx4){0,0,0,0};
#pragma unroll
        for (int kk = 0; kk < 2; kk++) {
            short8 af = *reinterpret_cast<const short8*>(Wb + (ms * 16 + l15) * 72 + kk * 32 + lh * 8);
            uf[0] = __builtin_amdgcn_mfma_f32_16x16x32_bf16(af, tfr[0][kk], uf[0], 0, 0, 0);
            uf[1] = __builtin_amdgcn_mfma_f32_16x16x32_bf16(af, tfr[1][kk], uf[1], 0, 0, 0);
        }
#pragma unroll
        for (int nt = 0; nt < 2; nt++)
#pragma unroll
            for (int j = 0; j < 4; j++)
                Ub[(ms * 16 + lh * 4 + j) * 72 + ns * 32 + nt * 16 + l15] = f32_to_bf16(uf[nt][j]);
        __syncthreads();

        // -------- state: S = gend*S + U*KlT --------
#pragma unroll
        for (int i = 0; i < 8; i++) st[i] = st[i] * ge;
#pragma unroll
        for (int kk = 0; kk < 2; kk++) {
            short8 af = *reinterpret_cast<const short8*>(Ub + (ms * 16 + l15) * 72 + kk * 32 + lh * 8);
#pragma unroll
            for (int nt = 0; nt < 8; nt++) {
                short8 bf = *reinterpret_cast<const short8*>(KlTB + (ns * 128 + nt * 16 + l15) * 72 + kk * 32 + lh * 8);
                st[nt] = __builtin_amdgcn_mfma_f32_16x16x32_bf16(af, bf, st[nt], 0, 0, 0);
            }
        }
        // bf16 shadow for next chunk
#pragma unroll
        for (int nt = 0; nt < 8; nt++)
#pragma unroll
            for (int j = 0; j < 4; j++)
                SbT[(ms * 16 + lh * 4 + j) * 264 + ns * 128 + nt * 16 + l15] = f32_to_bf16(st[nt][j]);

        // -------- O = X2 + U*A --------
#pragma unroll
        for (int kk = 0; kk < 2; kk++) {
            short8 af = *reinterpret_cast<const short8*>(Ub + (ms * 16 + l15) * 72 + kk * 32 + lh * 8);
            x2f[0] = __builtin_amdgcn_mfma_f32_16x16x32_bf16(af, afr[0][kk], x2f[0], 0, 0, 0);
            x2f[1] = __builtin_amdgcn_mfma_f32_16x16x32_bf16(af, afr[1][kk], x2f[1], 0, 0, 0);
        }
#pragma unroll
        for (int nt = 0; nt < 2; nt++)
#pragma unroll
            for (int j = 0; j < 4; j++)
                Ost[(ns * 32 + nt * 16 + l15) * 40 + ms * 16 + lh * 4 + j] = x2f[nt][j];
        __syncthreads();
        // coalesced store
        int orow = tid >> 2, oseg = (tid & 3) * 8;
        float4 o0 = *reinterpret_cast<const float4*>(Ost + orow * 40 + oseg);
        float4 o1 = *reinterpret_cast<const float4*>(Ost + orow * 40 + oseg + 4);
        size_t ga = ((size_t)(b * T_ + c * CC + orow)) * VAL_DIM + h * DV + dvbase + oseg;
        *reinterpret_cast<float4*>(O + ga) = o0;
        *reinterpret_cast<float4*>(O + ga + 4) = o1;
    }
}

// ---------------- gated RMSNorm * w * silu(g) -> bf16 ----------------
__global__ __launch_bounds__(256) void gated_norm_kernel(const float* __restrict__ o,
                                                         const float* __restrict__ g,
                                                         const float* __restrict__ nw,
                                                         unsigned short* __restrict__ out) {
    int bt = blockIdx.x, h = blockIdx.y, tid = threadIdx.x;
    const float* orow = o + (size_t)bt * VAL_DIM + h * DV;
    const float* grow = g + (size_t)bt * VAL_DIM + h * DV;
    float x0 = orow[tid], x1 = orow[tid + 256];
    float ss = x0 * x0 + x1 * x1;
#pragma unroll
    for (int m = 1; m < 64; m <<= 1) ss += __shfl_xor(ss, m);
    __shared__ float wsum[4];
    if ((tid & 63) == 0) wsum[tid >> 6] = ss;
    __syncthreads();
    float tot = wsum[0] + wsum[1] + wsum[2] + wsum[3];
    float r = rsqrtf(tot / (float)DV + EPS_);
    float o0 = x0 * r * nw[tid] * silu_f(grow[tid]);
    float o1 = x1 * r * nw[tid + 256] * silu_f(grow[tid + 256]);
    unsigned short* orow_o = out + (size_t)bt * VAL_DIM + h * DV;
    orow_o[tid] = f32_to_bf16(o0);
    orow_o[tid + 256] = f32_to_bf16(o1);
}

extern "C" void kernel_launch(void* const* d_in, const int* in_sizes, int n_in,
                              void* d_out, int out_size, void* d_ws, size_t ws_size,
                              hipStream_t stream) {
    const float* x     = (const float*)d_in[0];
    const float* w_q   = (const float*)d_in[1];
    const float* w_k   = (const float*)d_in[2];
    const float* w_v   = (const float*)d_in[3];
    const float* w_a   = (const float*)d_in[4];
    const float* w_b   = (const float*)d_in[5];
    const float* w_g   = (const float*)d_in[6];
    const float* w_o   = (const float*)d_in[7];
    const float* cq    = (const float*)d_in[8];
    const float* ck    = (const float*)d_in[9];
    const float* cv    = (const float*)d_in[10];
    const float* A_log = (const float*)d_in[11];
    const float* dtb   = (const float*)d_in[12];
    const float* nw    = (const float*)d_in[13];
    float* out = (float*)d_out;

    char* ws = (char*)d_ws;
    size_t off = 0;
    auto alloc = [&](size_t bytes) {
        char* p = ws + off;
        off += (bytes + 255) & ~(size_t)255;
        return p;
    };
    unsigned short* xb = (unsigned short*)alloc((size_t)MT * HID * 2);
    unsigned short* wT = (unsigned short*)alloc((size_t)VAL_DIM * HID * 2);
    float* P1 = (float*)alloc((size_t)MT * KEY_DIM * 4);   // proj scratch; later Qg+KB; later ONB
    float* QC = (float*)alloc((size_t)MT * KEY_DIM * 4);
    float* KC = (float*)alloc((size_t)MT * KEY_DIM * 4);
    float* P2 = (float*)alloc((size_t)MT * VAL_DIM * 4);   // g projection (f32)
    float* VC = (float*)alloc((size_t)MT * VAL_DIM * 4);   // conv v; later O (scan output)
    float* GL = (float*)alloc((size_t)MT * NH * 4);
    float* BE = (float*)alloc((size_t)MT * NH * 4);
    const int NCH = 12 * NC;  // total chunks
    unsigned short* KlT = (unsigned short*)alloc((size_t)NCH * 256 * 64 * 2);
    unsigned short* Tm  = (unsigned short*)alloc((size_t)NCH * 4096 * 2);
    unsigned short* Am  = (unsigned short*)alloc((size_t)NCH * 4096 * 2);
    unsigned short* BVT = (unsigned short*)alloc((size_t)NCH * 512 * 64 * 2);
    float* gend = (float*)alloc((size_t)NCH * 4);

    unsigned short* Qg = (unsigned short*)P1;                       // 12.58 MB
    unsigned short* KB = (unsigned short*)P1 + (size_t)NCH * 16384; // 12.58 MB
    float* OB = VC;                                                 // scan output reuses VC
    unsigned short* ONB = (unsigned short*)P1;                      // o_normed bf16 (after scan)

    // x -> bf16
    cvt_bf16_kernel<<<(MT * HID) / 1024, 256, 0, stream>>>(x, xb, MT * HID);

    // q path
    transpose_cvt_kernel<<<dim3(HID / 64, KEY_DIM / 64), 256, 0, stream>>>(w_q, wT, HID, KEY_DIM);
    gemm_bf16_kernel<<<dim3(KEY_DIM / BN, MT / BM), 256, 0, stream>>>(xb, wT, P1, MT, KEY_DIM, HID);
    conv_silu_l2norm_kernel<<<dim3(MT, NH), 256, 0, stream>>>(P1, cq, QC);

    // k path
    transpose_cvt_kernel<<<dim3(HID / 64, KEY_DIM / 64), 256, 0, stream>>>(w_k, wT, HID, KEY_DIM);
    gemm_bf16_kernel<<<dim3(KEY_DIM / BN, MT / BM), 256, 0, stream>>>(xb, wT, P1, MT, KEY_DIM, HID);
    conv_silu_l2norm_kernel<<<dim3(MT, NH), 256, 0, stream>>>(P1, ck, KC);

    // v path
    transpose_cvt_kernel<<<dim3(HID / 64, VAL_DIM / 64), 256, 0, stream>>>(w_v, wT, HID, VAL_DIM);
    gemm_bf16_kernel<<<dim3(VAL_DIM / BN, MT / BM), 256, 0, stream>>>(xb, wT, P2, MT, VAL_DIM, HID);
    conv_silu_kernel<<<dim3(MT, VAL_DIM / 256), 256, 0, stream>>>(P2, cv, VC);

    // g path (P2 free after conv consumed it)
    transpose_cvt_kernel<<<dim3(HID / 64, VAL_DIM / 64), 256, 0, stream>>>(w_g, wT, HID, VAL_DIM);
    gemm_bf16_kernel<<<dim3(VAL_DIM / BN, MT / BM), 256, 0, stream>>>(xb, wT, P2, MT, VAL_DIM, HID);

    // a/b projections (f32, exact)
    ab_kernel<<<MT, 256, 0, stream>>>(x, w_a, w_b, A_log, dtb, GL, BE);

    // chunked scan: pass 1 (chunk-parallel) then pass 2 (sequential over chunks)
    chunk_prep_kernel<<<dim3(NC, 12), 256, 0, stream>>>(QC, KC, VC, GL, BE,
                                                        Qg, KB, KlT, Tm, Am, BVT, gend);
    chunk_scan_kernel<<<dim3(16, 12), 256, 0, stream>>>(Qg, KB, KlT, Tm, Am, BVT, gend, OB);

    // gated RMSNorm -> bf16 (overwrites P1/Qg region, which is dead now)
    gated_norm_kernel<<<dim3(MT, NH), 256, 0, stream>>>(OB, P2, nw, ONB);

    // output projection
    transpose_cvt_kernel<<<dim3(VAL_DIM / 64, HID / 64), 256, 0, stream>>>(w_o, wT, VAL_DIM, HID);
    gemm_bf16_kernel<<<dim3(HID / BN, MT / BM), 256, 0, stream>>>(ONB, wT, out, MT, HID, VAL_DIM);
}

// Round 4
// 995.012 us; speedup vs baseline: 2.1171x; 1.1491x over previous
//
#include <hip/hip_runtime.h>
#include <hip/hip_bf16.h>
#include <cstdint>

#define B_ 2
#define T_ 2048
#define HID 2048
#define NH 6
#define DK 256
#define DV 512
#define KEY_DIM (NH*DK)   // 1536
#define VAL_DIM (NH*DV)   // 3072
#define EPS_ 1e-5f
#define SCALE_ 0.0625f
#define MT (B_*T_)        // 4096
#define CC 64             // chunk length
#define NC (T_/CC)        // 32 chunks per batch row

typedef __attribute__((ext_vector_type(8))) short short8;
typedef __attribute__((ext_vector_type(4))) float floatx4;
typedef __attribute__((ext_vector_type(4))) unsigned int uint4v;

union Pk8 { unsigned short us[8]; uint4v v; };

__device__ inline unsigned short f32_to_bf16(float f) {
    union { float f; unsigned int u; } v; v.f = f;
    unsigned int u = v.u;
    u += 0x7fffu + ((u >> 16) & 1u);
    return (unsigned short)(u >> 16);
}

__device__ inline float bf16_to_f32(unsigned short u) {
    union { unsigned int u; float f; } v; v.u = ((unsigned int)u) << 16;
    return v.f;
}

__device__ inline float silu_f(float x) { return x / (1.f + expf(-x)); }

// ---------------- convert f32 -> bf16 (elementwise) ----------------
__global__ __launch_bounds__(256) void cvt_bf16_kernel(const float* __restrict__ in,
                                                       unsigned short* __restrict__ out, int n) {
    int i = (blockIdx.x * 256 + threadIdx.x) * 4;
    if (i >= n) return;
    float4 v = *reinterpret_cast<const float4*>(in + i);
    ushort4 o;
    o.x = f32_to_bf16(v.x); o.y = f32_to_bf16(v.y);
    o.z = f32_to_bf16(v.z); o.w = f32_to_bf16(v.w);
    *reinterpret_cast<ushort4*>(out + i) = o;
}

// ---------------- transpose + convert: in f32 [K][N] -> out bf16 [N][K] ----------------
__global__ __launch_bounds__(256) void transpose_cvt_kernel(const float* __restrict__ in,
                                                            unsigned short* __restrict__ out,
                                                            int K, int N) {
    __shared__ float tile[64][65];
    int k0 = blockIdx.x * 64, n0 = blockIdx.y * 64;
    int r = threadIdx.x >> 2, c0 = (threadIdx.x & 3) * 16;
    const float* src = in + (size_t)(k0 + r) * N + n0 + c0;
#pragma unroll
    for (int j = 0; j < 16; j += 4) {
        float4 v = *reinterpret_cast<const float4*>(src + j);
        tile[r][c0 + j + 0] = v.x; tile[r][c0 + j + 1] = v.y;
        tile[r][c0 + j + 2] = v.z; tile[r][c0 + j + 3] = v.w;
    }
    __syncthreads();
    int n = threadIdx.x >> 2, kc = (threadIdx.x & 3) * 16;
    unsigned short* dst = out + (size_t)(n0 + n) * K + k0 + kc;
#pragma unroll
    for (int j = 0; j < 16; j += 4) {
        ushort4 o;
        o.x = f32_to_bf16(tile[kc + j + 0][n]);
        o.y = f32_to_bf16(tile[kc + j + 1][n]);
        o.z = f32_to_bf16(tile[kc + j + 2][n]);
        o.w = f32_to_bf16(tile[kc + j + 3][n]);
        *reinterpret_cast<ushort4*>(dst + j) = o;
    }
}

// ---------------- bf16 MFMA GEMM: C[M,N] = A[M,K] @ B[K,N], B given as BT[N,K] ----------------
#define BM 128
#define BN 128
#define BK 32
#define LDS_S 40   // bf16 elems per LDS row (32 + 8 pad)

__global__ __launch_bounds__(256) void gemm_bf16_kernel(const unsigned short* __restrict__ A,
                                                        const unsigned short* __restrict__ BT,
                                                        float* __restrict__ C,
                                                        int M, int N, int K) {
    __shared__ __align__(16) unsigned short As[BM * LDS_S];
    __shared__ __align__(16) unsigned short Bs[BN * LDS_S];
    int tid = threadIdx.x;
    int m0 = blockIdx.y * BM, n0 = blockIdx.x * BN;
    int wave = tid >> 6, lane = tid & 63;
    int wr = (wave >> 1) * 64, wc = (wave & 1) * 64;
    int l15 = lane & 15, lh = lane >> 4;

    int srow = tid >> 1, shalf = tid & 1;
    const unsigned short* agp = A + (size_t)(m0 + srow) * K + shalf * 16;
    const unsigned short* bgp = BT + (size_t)(n0 + srow) * K + shalf * 16;
    unsigned short* asl = As + srow * LDS_S + shalf * 16;
    unsigned short* bsl = Bs + srow * LDS_S + shalf * 16;

    floatx4 acc[4][4];
#pragma unroll
    for (int m = 0; m < 4; m++)
#pragma unroll
        for (int n = 0; n < 4; n++) acc[m][n] = (floatx4){0.f, 0.f, 0.f, 0.f};

    for (int kt = 0; kt < K; kt += BK) {
        uint4v av0 = *reinterpret_cast<const uint4v*>(agp + kt);
        uint4v av1 = *reinterpret_cast<const uint4v*>(agp + kt + 8);
        uint4v bv0 = *reinterpret_cast<const uint4v*>(bgp + kt);
        uint4v bv1 = *reinterpret_cast<const uint4v*>(bgp + kt + 8);
        __syncthreads();
        *reinterpret_cast<uint4v*>(asl) = av0;
        *reinterpret_cast<uint4v*>(asl + 8) = av1;
        *reinterpret_cast<uint4v*>(bsl) = bv0;
        *reinterpret_cast<uint4v*>(bsl + 8) = bv1;
        __syncthreads();
        short8 a[4], b[4];
#pragma unroll
        for (int i = 0; i < 4; i++)
            a[i] = *reinterpret_cast<const short8*>(As + (wr + i * 16 + l15) * LDS_S + lh * 8);
#pragma unroll
        for (int i = 0; i < 4; i++)
            b[i] = *reinterpret_cast<const short8*>(Bs + (wc + i * 16 + l15) * LDS_S + lh * 8);
#pragma unroll
        for (int m = 0; m < 4; m++)
#pragma unroll
            for (int n = 0; n < 4; n++)
                acc[m][n] = __builtin_amdgcn_mfma_f32_16x16x32_bf16(a[m], b[n], acc[m][n], 0, 0, 0);
    }

#pragma unroll
    for (int m = 0; m < 4; m++)
#pragma unroll
        for (int n = 0; n < 4; n++) {
            int row = m0 + wr + m * 16 + lh * 4;
            int col = n0 + wc + n * 16 + l15;
#pragma unroll
            for (int j = 0; j < 4; j++)
                C[(size_t)(row + j) * N + col] = acc[m][n][j];
        }
}

// ---------------- a/b projections + softplus/sigmoid ----------------
__global__ __launch_bounds__(256) void ab_kernel(const float* __restrict__ x,
                                                 const float* __restrict__ wa,
                                                 const float* __restrict__ wb,
                                                 const float* __restrict__ A_log,
                                                 const float* __restrict__ dtb,
                                                 float* __restrict__ glog,
                                                 float* __restrict__ beta) {
    int bt = blockIdx.x, tid = threadIdx.x;
    const float* xr = x + (size_t)bt * HID;
    float pa[NH], pb[NH];
#pragma unroll
    for (int h = 0; h < NH; h++) { pa[h] = 0.f; pb[h] = 0.f; }
    for (int k = tid; k < HID; k += 256) {
        float xv = xr[k];
#pragma unroll
        for (int h = 0; h < NH; h++) {
            pa[h] = fmaf(xv, wa[k * NH + h], pa[h]);
            pb[h] = fmaf(xv, wb[k * NH + h], pb[h]);
        }
    }
    __shared__ float red[256][12];
#pragma unroll
    for (int h = 0; h < NH; h++) { red[tid][h] = pa[h]; red[tid][NH + h] = pb[h]; }
    __syncthreads();
    for (int s = 128; s > 0; s >>= 1) {
        if (tid < s)
#pragma unroll
            for (int j = 0; j < 12; j++) red[tid][j] += red[tid + s][j];
        __syncthreads();
    }
    if (tid < NH) {
        float a = red[0][tid] + dtb[tid];
        float sp = (a > 20.f) ? a : log1pf(expf(a));
        glog[(size_t)bt * NH + tid] = -expf(A_log[tid]) * sp;
        float bv = red[0][NH + tid];
        beta[(size_t)bt * NH + tid] = 1.f / (1.f + expf(-bv));
    }
}

// ---------------- causal conv(4) + SiLU + per-head l2norm (q,k) ----------------
__global__ __launch_bounds__(256) void conv_silu_l2norm_kernel(const float* __restrict__ in,
                                                               const float* __restrict__ w,
                                                               float* __restrict__ out) {
    int bt = blockIdx.x;
    int h = blockIdx.y;
    int t = bt & (T_ - 1);
    int c = h * DK + threadIdx.x;
    float4 wv = *reinterpret_cast<const float4*>(w + (size_t)c * 4);
    float acc = 0.f;
    if (t >= 3) {
        acc = in[(size_t)(bt - 3) * KEY_DIM + c] * wv.x
            + in[(size_t)(bt - 2) * KEY_DIM + c] * wv.y
            + in[(size_t)(bt - 1) * KEY_DIM + c] * wv.z
            + in[(size_t)(bt) * KEY_DIM + c] * wv.w;
    } else {
        if (t - 3 >= 0) acc = fmaf(in[(size_t)(bt - 3) * KEY_DIM + c], wv.x, acc);
        if (t - 2 >= 0) acc = fmaf(in[(size_t)(bt - 2) * KEY_DIM + c], wv.y, acc);
        if (t - 1 >= 0) acc = fmaf(in[(size_t)(bt - 1) * KEY_DIM + c], wv.z, acc);
        acc = fmaf(in[(size_t)bt * KEY_DIM + c], wv.w, acc);
    }
    float s = silu_f(acc);
    float ss = s * s;
#pragma unroll
    for (int m = 1; m < 64; m <<= 1) ss += __shfl_xor(ss, m);
    __shared__ float wsum[4];
    if ((threadIdx.x & 63) == 0) wsum[threadIdx.x >> 6] = ss;
    __syncthreads();
    float tot = wsum[0] + wsum[1] + wsum[2] + wsum[3];
    float r = 1.f / fmaxf(sqrtf(tot), 1e-6f);
    out[(size_t)bt * KEY_DIM + c] = s * r;
}

// ---------------- causal conv(4) + SiLU (v) ----------------
__global__ __launch_bounds__(256) void conv_silu_kernel(const float* __restrict__ in,
                                                        const float* __restrict__ w,
                                                        float* __restrict__ out) {
    int bt = blockIdx.x;
    int c = blockIdx.y * 256 + threadIdx.x;
    int t = bt & (T_ - 1);
    float4 wv = *reinterpret_cast<const float4*>(w + (size_t)c * 4);
    float acc = 0.f;
    if (t >= 3) {
        acc = in[(size_t)(bt - 3) * VAL_DIM + c] * wv.x
            + in[(size_t)(bt - 2) * VAL_DIM + c] * wv.y
            + in[(size_t)(bt - 1) * VAL_DIM + c] * wv.z
            + in[(size_t)(bt) * VAL_DIM + c] * wv.w;
    } else {
        if (t - 3 >= 0) acc = fmaf(in[(size_t)(bt - 3) * VAL_DIM + c], wv.x, acc);
        if (t - 2 >= 0) acc = fmaf(in[(size_t)(bt - 2) * VAL_DIM + c], wv.y, acc);
        if (t - 1 >= 0) acc = fmaf(in[(size_t)(bt - 1) * VAL_DIM + c], wv.z, acc);
        acc = fmaf(in[(size_t)bt * VAL_DIM + c], wv.w, acc);
    }
    out[(size_t)bt * VAL_DIM + c] = silu_f(acc);
}

// ================= chunked gated delta rule =================
// Pass 1 (chunk-parallel): per (bh, chunk): decays, KK^T/QK^T (MFMA), M,
// T = (I+M)^-1 (register/readlane forward substitution), pre-scaled bf16 operands.
__global__ __launch_bounds__(256) void chunk_prep_kernel(
    const float* __restrict__ QC, const float* __restrict__ KC, const float* __restrict__ VC,
    const float* __restrict__ GL, const float* __restrict__ BE,
    unsigned short* __restrict__ Qg, unsigned short* __restrict__ KB,
    unsigned short* __restrict__ KlT, unsigned short* __restrict__ Tm,
    unsigned short* __restrict__ Am, unsigned short* __restrict__ BVT,
    float* __restrict__ gend) {
    int c = blockIdx.x;       // chunk within batch-row
    int bh = blockIdx.y;      // b*NH + h
    int b = bh / NH, h = bh % NH;
    size_t idx = (size_t)bh * NC + c;
    int bt0 = b * T_ + c * CC;

    // 67584 B shared buffer, multiple overlays:
    //   [0,33792)      : Kb bf16 [64][264]           (dies after KlT)
    //   [33792,67584)  : Qb bf16 [64][264]           (dies after Qg/KB rescale)
    //       overlay    : Msf f32 [64][65]  @ +33792  (16640 B)
    //       overlay    : Ts  bf16[64][72]  @ +50432  (9216 B)
    //   whole buffer   : Vst f32 [64][264]           (BVT section)
    __shared__ __align__(16) char ldsbuf[64 * 264 * 2 * 2];
    unsigned short* Kb = (unsigned short*)ldsbuf;
    unsigned short* Qb = (unsigned short*)(ldsbuf + 33792);
    float* Vst = (float*)ldsbuf;
    float* Msf = (float*)(ldsbuf + 33792);
    unsigned short* Ts_lds = (unsigned short*)(ldsbuf + 50432);
    __shared__ float gc[64], es[64], bb_s[64], gtmp[64];

    int tid = threadIdx.x, wave = tid >> 6, lane = tid & 63;
    int l15 = lane & 15, lh = lane >> 4;

    if (tid < 64) {
        gtmp[tid] = GL[(size_t)(bt0 + tid) * NH + h];
        bb_s[tid] = BE[(size_t)(bt0 + tid) * NH + h];
    }

    // stage K, Q chunk as bf16 [64][264]
    {
        int r = tid >> 2, seg = (tid & 3) * 64;
        const float* ksrc = KC + (size_t)(bt0 + r) * KEY_DIM + h * DK + seg;
        const float* qsrc = QC + (size_t)(bt0 + r) * KEY_DIM + h * DK + seg;
#pragma unroll
        for (int jj = 0; jj < 8; jj++) {
            float4 a = *reinterpret_cast<const float4*>(ksrc + jj * 8);
            float4 a2 = *reinterpret_cast<const float4*>(ksrc + jj * 8 + 4);
            Pk8 pk;
            pk.us[0] = f32_to_bf16(a.x);  pk.us[1] = f32_to_bf16(a.y);
            pk.us[2] = f32_to_bf16(a.z);  pk.us[3] = f32_to_bf16(a.w);
            pk.us[4] = f32_to_bf16(a2.x); pk.us[5] = f32_to_bf16(a2.y);
            pk.us[6] = f32_to_bf16(a2.z); pk.us[7] = f32_to_bf16(a2.w);
            *reinterpret_cast<uint4v*>(Kb + r * 264 + seg + jj * 8) = pk.v;
            float4 qa = *reinterpret_cast<const float4*>(qsrc + jj * 8);
            float4 qa2 = *reinterpret_cast<const float4*>(qsrc + jj * 8 + 4);
            pk.us[0] = f32_to_bf16(qa.x);  pk.us[1] = f32_to_bf16(qa.y);
            pk.us[2] = f32_to_bf16(qa.z);  pk.us[3] = f32_to_bf16(qa.w);
            pk.us[4] = f32_to_bf16(qa2.x); pk.us[5] = f32_to_bf16(qa2.y);
            pk.us[6] = f32_to_bf16(qa2.z); pk.us[7] = f32_to_bf16(qa2.w);
            *reinterpret_cast<uint4v*>(Qb + r * 264 + seg + jj * 8) = pk.v;
        }
    }
    __syncthreads();

    // wave 0: shuffle-based inclusive prefix sum of g
    if (wave == 0) {
        float xg = gtmp[lane];
#pragma unroll
        for (int off = 1; off < 64; off <<= 1) {
            float yg = __shfl_up(xg, off, 64);
            if (lane >= off) xg += yg;
        }
        gc[lane] = xg;
    }

    // KK^T and QK^T via MFMA (wave w owns t-rows 16w..16w+15)
    floatx4 kkf[4], qkf[4];
#pragma unroll
    for (int nt = 0; nt < 4; nt++) { kkf[nt] = (floatx4){0,0,0,0}; qkf[nt] = (floatx4){0,0,0,0}; }
#pragma unroll
    for (int kk = 0; kk < 8; kk++) {
        short8 ak = *reinterpret_cast<const short8*>(Kb + (wave * 16 + l15) * 264 + kk * 32 + lh * 8);
        short8 aq = *reinterpret_cast<const short8*>(Qb + (wave * 16 + l15) * 264 + kk * 32 + lh * 8);
#pragma unroll
        for (int nt = 0; nt < 4; nt++) {
            short8 bk = *reinterpret_cast<const short8*>(Kb + (nt * 16 + l15) * 264 + kk * 32 + lh * 8);
            kkf[nt] = __builtin_amdgcn_mfma_f32_16x16x32_bf16(ak, bk, kkf[nt], 0, 0, 0);
            qkf[nt] = __builtin_amdgcn_mfma_f32_16x16x32_bf16(aq, bk, qkf[nt], 0, 0, 0);
        }
    }
    __syncthreads();   // gc ready; all Qb/Kb MFMA reads done

    // Qg = SCALE*gamma_t*q ; KB = b_t*gamma_t*k  (rescale from staged bf16 tiles)
    {
        int r = tid >> 2, seg = (tid & 3) * 64;
        float gmm = __expf(gc[r]);
        float qs = SCALE_ * gmm, ksc = bb_s[r] * gmm;
#pragma unroll
        for (int jj = 0; jj < 8; jj++) {
            Pk8 qi, ki, qo, ko;
            qi.v = *reinterpret_cast<const uint4v*>(Qb + r * 264 + seg + jj * 8);
            ki.v = *reinterpret_cast<const uint4v*>(Kb + r * 264 + seg + jj * 8);
#pragma unroll
            for (int e = 0; e < 8; e++) {
                qo.us[e] = f32_to_bf16(bf16_to_f32(qi.us[e]) * qs);
                ko.us[e] = f32_to_bf16(bf16_to_f32(ki.us[e]) * ksc);
            }
            *reinterpret_cast<uint4v*>(Qg + idx * 16384 + r * 256 + seg + jj * 8) = qo.v;
            *reinterpret_cast<uint4v*>(KB + idx * 16384 + r * 256 + seg + jj * 8) = ko.v;
        }
    }
    if (tid < 64) es[tid] = __expf(gc[63] - gc[tid]);
    __syncthreads();   // Qb reads complete before Msf overlay

    // M (LDS overlay over Qb) and A (global bf16)
#pragma unroll
    for (int nt = 0; nt < 4; nt++)
#pragma unroll
        for (int j = 0; j < 4; j++) {
            int t2 = wave * 16 + lh * 4 + j;
            int s2 = nt * 16 + l15;
            float dec = (s2 <= t2) ? __expf(gc[t2] - gc[s2]) : 0.f;
            Msf[t2 * 65 + s2] = (s2 < t2) ? bb_s[t2] * dec * kkf[nt][j] : 0.f;
            float av = (s2 <= t2) ? SCALE_ * dec * qkf[nt][j] : 0.f;
            Am[idx * 4096 + t2 * 64 + s2] = f32_to_bf16(av);
        }
    __syncthreads();

    // T = (I+M)^-1 by register/readlane forward substitution.
    // Wave w owns columns j = 4*j2 + w (j2=0..15); lane = row t.
    // a[j2] accumulates sum_{s} M[t][s]*T[s][j]; final T[t][j] = -a[j2] (t>j).
    {
        int t = lane;
        float a[16];
#pragma unroll
        for (int j2 = 0; j2 < 16; j2++) a[j2] = 0.f;
        float mcur = Msf[t * 65 + 0];
        for (int s = 0; s < 63; s++) {
            float mnext = Msf[t * 65 + s + 1];
            float m = (t > s) ? mcur : 0.f;
#pragma unroll
            for (int j2 = 0; j2 < 16; j2++) {
                int jg = 4 * j2 + wave;       // wave-uniform
                if (jg < s) {                 // uniform branch
                    float ra = __int_as_float(
                        __builtin_amdgcn_readlane(__float_as_int(a[j2]), s));
                    a[j2] = fmaf(m, -ra, a[j2]);
                } else if (jg == s) {
                    a[j2] += m;               // T[s][s] = 1
                }
            }
            mcur = mnext;
        }
        // stage T (bf16) for coalesced store
#pragma unroll
        for (int j2 = 0; j2 < 16; j2++) {
            int jg = 4 * j2 + wave;
            float v = (t == jg) ? 1.f : ((jg < t) ? -a[j2] : 0.f);
            Ts_lds[t * 72 + jg] = f32_to_bf16(v);
        }
    }
    __syncthreads();

    // store T (bf16, coalesced)
    {
        int rr = tid >> 2, sseg = (tid & 3) * 16;
        *reinterpret_cast<uint4v*>(Tm + idx * 4096 + rr * 64 + sseg) =
            *reinterpret_cast<const uint4v*>(Ts_lds + rr * 72 + sseg);
        *reinterpret_cast<uint4v*>(Tm + idx * 4096 + rr * 64 + sseg + 8) =
            *reinterpret_cast<const uint4v*>(Ts_lds + rr * 72 + sseg + 8);
    }
    // KlT[dk][s] = k_s[dk] * (gammaEnd/gamma_s)
    {
        int dk = tid;
#pragma unroll
        for (int sb = 0; sb < 8; sb++) {
            Pk8 pk;
#pragma unroll
            for (int e = 0; e < 8; e++) {
                int s = sb * 8 + e;
                pk.us[e] = f32_to_bf16(bf16_to_f32(Kb[s * 264 + dk]) * es[s]);
            }
            *reinterpret_cast<uint4v*>(KlT + idx * 16384 + dk * 64 + sb * 8) = pk.v;
        }
    }
    // BVT[dv][c] = b_c * v_c[dv] (transpose through LDS, two halves)
    for (int hv = 0; hv < 2; hv++) {
        __syncthreads();  // prior LDS readers done / prev half done
        int r = tid >> 2, seg = (tid & 3) * 64;
        const float* vsrc = VC + (size_t)(bt0 + r) * VAL_DIM + h * DV + hv * 256 + seg;
#pragma unroll
        for (int jj = 0; jj < 16; jj++)
            *reinterpret_cast<float4*>(Vst + r * 264 + seg + jj * 4) =
                *reinterpret_cast<const float4*>(vsrc + jj * 4);
        __syncthreads();
#pragma unroll
        for (int sb = 0; sb < 8; sb++) {
            Pk8 pk;
#pragma unroll
            for (int e = 0; e < 8; e++) {
                int s = sb * 8 + e;
                pk.us[e] = f32_to_bf16(Vst[s * 264 + tid] * bb_s[s]);
            }
            *reinterpret_cast<uint4v*>(BVT + idx * 32768 + (size_t)(hv * 256 + tid) * 64 + sb * 8) = pk.v;
        }
    }
    if (tid == 0) gend[idx] = __expf(gc[63]);
}

// Pass 2: sequential over chunks; block = (dv-slice of 32, bh). State S^T [32][256]
// kept in f32 MFMA accumulators across chunks; bf16 shadow in LDS for operands.
__global__ __launch_bounds__(256, 1) void chunk_scan_kernel(
    const unsigned short* __restrict__ Qg, const unsigned short* __restrict__ KBp,
    const unsigned short* __restrict__ KlTp, const unsigned short* __restrict__ Tmp_,
    const unsigned short* __restrict__ Amp_, const unsigned short* __restrict__ BVTp,
    const float* __restrict__ gendp, float* __restrict__ O) {
    int slice = blockIdx.x;   // 0..15
    int bh = blockIdx.y;      // 0..11
    int b = bh / NH, h = bh % NH;
    int dvbase = slice * 32;
    int tid = threadIdx.x, wave = tid >> 6, lane = tid & 63;
    int l15 = lane & 15, lh = lane >> 4;
    int ms = wave >> 1;       // dv row strip (16 rows)
    int ns = wave & 1;        // column half

    __shared__ __align__(16) unsigned short QgB[64 * 264];
    __shared__ __align__(16) unsigned short KBB[64 * 264];
    __shared__ __align__(16) unsigned short KlTB[256 * 72];
    __shared__ __align__(16) unsigned short SbT[32 * 264];
    __shared__ __align__(16) unsigned short Wb[32 * 72];
    __shared__ __align__(16) unsigned short Ub[32 * 72];
    __shared__ __align__(16) float Ost[64 * 40];

    floatx4 st[8];
#pragma unroll
    for (int i = 0; i < 8; i++) st[i] = (floatx4){0.f, 0.f, 0.f, 0.f};
    for (int i = tid; i < 32 * 264; i += 256) SbT[i] = 0;

    int r = tid >> 2, seg = (tid & 3) * 64;

    for (int c = 0; c < NC; c++) {
        size_t idx = (size_t)bh * NC + c;
        const unsigned short* qg = Qg + idx * 16384;
        const unsigned short* kb = KBp + idx * 16384;
        const unsigned short* kl = KlTp + idx * 16384;
        const unsigned short* tm = Tmp_ + idx * 4096;
        const unsigned short* am = Amp_ + idx * 4096;
        const unsigned short* bvt = BVTp + idx * 32768;

        // -------- prefetch (registers) --------
        float ge = gendp[idx];
        short8 tfr[2][2], afr[2][2];
#pragma unroll
        for (int nt = 0; nt < 2; nt++)
#pragma unroll
            for (int kk = 0; kk < 2; kk++) {
                int tcol = ns * 32 + nt * 16 + l15;
                tfr[nt][kk] = *reinterpret_cast<const short8*>(tm + tcol * 64 + kk * 32 + lh * 8);
                afr[nt][kk] = *reinterpret_cast<const short8*>(am + tcol * 64 + kk * 32 + lh * 8);
            }
        float bvv[2][4];
#pragma unroll
        for (int nt = 0; nt < 2; nt++)
#pragma unroll
            for (int j = 0; j < 4; j++)
                bvv[nt][j] = bf16_to_f32(bvt[(size_t)(dvbase + ms * 16 + lh * 4 + j) * 64
                                             + ns * 32 + nt * 16 + l15]);
        uint4v qv[8], kv[8], klv[8];
#pragma unroll
        for (int j = 0; j < 8; j++) {
            qv[j] = *reinterpret_cast<const uint4v*>(qg + r * 256 + seg + j * 8);
            kv[j] = *reinterpret_cast<const uint4v*>(kb + r * 256 + seg + j * 8);
        }
#pragma unroll
        for (int j = 0; j < 8; j++)
            klv[j] = *reinterpret_cast<const uint4v*>(kl + tid * 64 + j * 8);

        __syncthreads();   // all waves done with previous chunk's buffers
#pragma unroll
        for (int j = 0; j < 8; j++) {
            *reinterpret_cast<uint4v*>(QgB + r * 264 + seg + j * 8) = qv[j];
            *reinterpret_cast<uint4v*>(KBB + r * 264 + seg + j * 8) = kv[j];
        }
#pragma unroll
        for (int j = 0; j < 8; j++)
            *reinterpret_cast<uint4v*>(KlTB + tid * 72 + j * 8) = klv[j];
        __syncthreads();

        // -------- X2 = Sb^T*Qg , X1 = Sb^T*KB --------
        floatx4 x2f[2], x1f[2];
#pragma unroll
        for (int nt = 0; nt < 2; nt++) { x2f[nt] = (floatx4){0,0,0,0}; x1f[nt] = (floatx4){0,0,0,0}; }
#pragma unroll
        for (int kk = 0; kk < 8; kk++) {
            short8 af = *reinterpret_cast<const short8*>(SbT + (ms * 16 + l15) * 264 + kk * 32 + lh * 8);
#pragma unroll
            for (int nt = 0; nt < 2; nt++) {
                short8 bq = *reinterpret_cast<const short8*>(QgB + (ns * 32 + nt * 16 + l15) * 264 + kk * 32 + lh * 8);
                short8 bk = *reinterpret_cast<const short8*>(KBB + (ns * 32 + nt * 16 + l15) * 264 + kk * 32 + lh * 8);
                x2f[nt] = __builtin_amdgcn_mfma_f32_16x16x32_bf16(af, bq, x2f[nt], 0, 0, 0);
                x1f[nt] = __builtin_amdgcn_mfma_f32_16x16x32_bf16(af, bk, x1f[nt], 0, 0, 0);
            }
        }
        // W = BV - X1  -> bf16 LDS
#pragma unroll
        for (int nt = 0; nt < 2; nt++)
#pragma unroll
            for (int j = 0; j < 4; j++)
                Wb[(ms * 16 + lh * 4 + j) * 72 + ns * 32 + nt * 16 + l15] =
                    f32_to_bf16(bvv[nt][j] - x1f[nt][j]);
        __syncthreads();

        // -------- U = W * T --------
        floatx4 uf[2];
#pragma unroll
        for (int nt = 0; nt < 2; nt++) uf[nt] = (floatx4){0,0,0,0};
#pragma unroll
        for (int kk = 0; kk < 2; kk++) {
            short8 af = *reinterpret_cast<const short8*>(Wb + (ms * 16 + l15) * 72 + kk * 32 + lh * 8);
            uf[0] = __builtin_amdgcn_mfma_f32_16x16x32_bf16(af, tfr[0][kk], uf[0], 0, 0, 0);
            uf[1] = __builtin_amdgcn_mfma_f32_16x16x32_bf16(af, tfr[1][kk], uf[1], 0, 0, 0);
        }
#pragma unroll
        for (int nt = 0; nt < 2; nt++)
#pragma unroll
            for (int j = 0; j < 4; j++)
                Ub[(ms * 16 + lh * 4 + j) * 72 + ns * 32 + nt * 16 + l15] = f32_to_bf16(uf[nt][j]);
        __syncthreads();

        // -------- state: S = gend*S + U*KlT --------
#pragma unroll
        for (int i = 0; i < 8; i++) st[i] = st[i] * ge;
#pragma unroll
        for (int kk = 0; kk < 2; kk++) {
            short8 af = *reinterpret_cast<const short8*>(Ub + (ms * 16 + l15) * 72 + kk * 32 + lh * 8);
#pragma unroll
            for (int nt = 0; nt < 8; nt++) {
                short8 bf = *reinterpret_cast<const short8*>(KlTB + (ns * 128 + nt * 16 + l15) * 72 + kk * 32 + lh * 8);
                st[nt] = __builtin_amdgcn_mfma_f32_16x16x32_bf16(af, bf, st[nt], 0, 0, 0);
            }
        }
        // bf16 shadow for next chunk
#pragma unroll
        for (int nt = 0; nt < 8; nt++)
#pragma unroll
            for (int j = 0; j < 4; j++)
                SbT[(ms * 16 + lh * 4 + j) * 264 + ns * 128 + nt * 16 + l15] = f32_to_bf16(st[nt][j]);

        // -------- O = X2 + U*A --------
#pragma unroll
        for (int kk = 0; kk < 2; kk++) {
            short8 af = *reinterpret_cast<const short8*>(Ub + (ms * 16 + l15) * 72 + kk * 32 + lh * 8);
            x2f[0] = __builtin_amdgcn_mfma_f32_16x16x32_bf16(af, afr[0][kk], x2f[0], 0, 0, 0);
            x2f[1] = __builtin_amdgcn_mfma_f32_16x16x32_bf16(af, afr[1][kk], x2f[1], 0, 0, 0);
        }
#pragma unroll
        for (int nt = 0; nt < 2; nt++)
#pragma unroll
            for (int j = 0; j < 4; j++)
                Ost[(ns * 32 + nt * 16 + l15) * 40 + ms * 16 + lh * 4 + j] = x2f[nt][j];
        __syncthreads();
        // coalesced store
        int orow = tid >> 2, oseg = (tid & 3) * 8;
        float4 o0 = *reinterpret_cast<const float4*>(Ost + orow * 40 + oseg);
        float4 o1 = *reinterpret_cast<const float4*>(Ost + orow * 40 + oseg + 4);
        size_t ga = ((size_t)(b * T_ + c * CC + orow)) * VAL_DIM + h * DV + dvbase + oseg;
        *reinterpret_cast<float4*>(O + ga) = o0;
        *reinterpret_cast<float4*>(O + ga + 4) = o1;
    }
}

// ---------------- gated RMSNorm * w * silu(g) -> bf16 ----------------
__global__ __launch_bounds__(256) void gated_norm_kernel(const float* __restrict__ o,
                                                         const float* __restrict__ g,
                                                         const float* __restrict__ nw,
                                                         unsigned short* __restrict__ out) {
    int bt = blockIdx.x, h = blockIdx.y, tid = threadIdx.x;
    const float* orow = o + (size_t)bt * VAL_DIM + h * DV;
    const float* grow = g + (size_t)bt * VAL_DIM + h * DV;
    float x0 = orow[tid], x1 = orow[tid + 256];
    float ss = x0 * x0 + x1 * x1;
#pragma unroll
    for (int m = 1; m < 64; m <<= 1) ss += __shfl_xor(ss, m);
    __shared__ float wsum[4];
    if ((tid & 63) == 0) wsum[tid >> 6] = ss;
    __syncthreads();
    float tot = wsum[0] + wsum[1] + wsum[2] + wsum[3];
    float r = rsqrtf(tot / (float)DV + EPS_);
    float o0 = x0 * r * nw[tid] * silu_f(grow[tid]);
    float o1 = x1 * r * nw[tid + 256] * silu_f(grow[tid + 256]);
    unsigned short* orow_o = out + (size_t)bt * VAL_DIM + h * DV;
    orow_o[tid] = f32_to_bf16(o0);
    orow_o[tid + 256] = f32_to_bf16(o1);
}

extern "C" void kernel_launch(void* const* d_in, const int* in_sizes, int n_in,
                              void* d_out, int out_size, void* d_ws, size_t ws_size,
                              hipStream_t stream) {
    const float* x     = (const float*)d_in[0];
    const float* w_q   = (const float*)d_in[1];
    const float* w_k   = (const float*)d_in[2];
    const float* w_v   = (const float*)d_in[3];
    const float* w_a   = (const float*)d_in[4];
    const float* w_b   = (const float*)d_in[5];
    const float* w_g   = (const float*)d_in[6];
    const float* w_o   = (const float*)d_in[7];
    const float* cq    = (const float*)d_in[8];
    const float* ck    = (const float*)d_in[9];
    const float* cv    = (const float*)d_in[10];
    const float* A_log = (const float*)d_in[11];
    const float* dtb   = (const float*)d_in[12];
    const float* nw    = (const float*)d_in[13];
    float* out = (float*)d_out;

    char* ws = (char*)d_ws;
    size_t off = 0;
    auto alloc = [&](size_t bytes) {
        char* p = ws + off;
        off += (bytes + 255) & ~(size_t)255;
        return p;
    };
    unsigned short* xb = (unsigned short*)alloc((size_t)MT * HID * 2);
    unsigned short* wT = (unsigned short*)alloc((size_t)VAL_DIM * HID * 2);
    float* P1 = (float*)alloc((size_t)MT * KEY_DIM * 4);   // proj scratch; later Qg+KB; later ONB
    float* QC = (float*)alloc((size_t)MT * KEY_DIM * 4);
    float* KC = (float*)alloc((size_t)MT * KEY_DIM * 4);
    float* P2 = (float*)alloc((size_t)MT * VAL_DIM * 4);   // g projection (f32)
    float* VC = (float*)alloc((size_t)MT * VAL_DIM * 4);   // conv v; later O (scan output)
    float* GL = (float*)alloc((size_t)MT * NH * 4);
    float* BE = (float*)alloc((size_t)MT * NH * 4);
    const int NCH = 12 * NC;  // total chunks
    unsigned short* KlT = (unsigned short*)alloc((size_t)NCH * 256 * 64 * 2);
    unsigned short* Tm  = (unsigned short*)alloc((size_t)NCH * 4096 * 2);
    unsigned short* Am  = (unsigned short*)alloc((size_t)NCH * 4096 * 2);
    unsigned short* BVT = (unsigned short*)alloc((size_t)NCH * 512 * 64 * 2);
    float* gend = (float*)alloc((size_t)NCH * 4);

    unsigned short* Qg = (unsigned short*)P1;                       // 12.58 MB
    unsigned short* KB = (unsigned short*)P1 + (size_t)NCH * 16384; // 12.58 MB
    float* OB = VC;                                                 // scan output reuses VC
    unsigned short* ONB = (unsigned short*)P1;                      // o_normed bf16 (after scan)

    // x -> bf16
    cvt_bf16_kernel<<<(MT * HID) / 1024, 256, 0, stream>>>(x, xb, MT * HID);

    // q path
    transpose_cvt_kernel<<<dim3(HID / 64, KEY_DIM / 64), 256, 0, stream>>>(w_q, wT, HID, KEY_DIM);
    gemm_bf16_kernel<<<dim3(KEY_DIM / BN, MT / BM), 256, 0, stream>>>(xb, wT, P1, MT, KEY_DIM, HID);
    conv_silu_l2norm_kernel<<<dim3(MT, NH), 256, 0, stream>>>(P1, cq, QC);

    // k path
    transpose_cvt_kernel<<<dim3(HID / 64, KEY_DIM / 64), 256, 0, stream>>>(w_k, wT, HID, KEY_DIM);
    gemm_bf16_kernel<<<dim3(KEY_DIM / BN, MT / BM), 256, 0, stream>>>(xb, wT, P1, MT, KEY_DIM, HID);
    conv_silu_l2norm_kernel<<<dim3(MT, NH), 256, 0, stream>>>(P1, ck, KC);

    // v path
    transpose_cvt_kernel<<<dim3(HID / 64, VAL_DIM / 64), 256, 0, stream>>>(w_v, wT, HID, VAL_DIM);
    gemm_bf16_kernel<<<dim3(VAL_DIM / BN, MT / BM), 256, 0, stream>>>(xb, wT, P2, MT, VAL_DIM, HID);
    conv_silu_kernel<<<dim3(MT, VAL_DIM / 256), 256, 0, stream>>>(P2, cv, VC);

    // g path (P2 free after conv consumed it)
    transpose_cvt_kernel<<<dim3(HID / 64, VAL_DIM / 64), 256, 0, stream>>>(w_g, wT, HID, VAL_DIM);
    gemm_bf16_kernel<<<dim3(VAL_DIM / BN, MT / BM), 256, 0, stream>>>(xb, wT, P2, MT, VAL_DIM, HID);

    // a/b projections (f32, exact)
    ab_kernel<<<MT, 256, 0, stream>>>(x, w_a, w_b, A_log, dtb, GL, BE);

    // chunked scan: pass 1 (chunk-parallel) then pass 2 (sequential over chunks)
    chunk_prep_kernel<<<dim3(NC, 12), 256, 0, stream>>>(QC, KC, VC, GL, BE,
                                                        Qg, KB, KlT, Tm, Am, BVT, gend);
    chunk_scan_kernel<<<dim3(16, 12), 256, 0, stream>>>(Qg, KB, KlT, Tm, Am, BVT, gend, OB);

    // gated RMSNorm -> bf16 (overwrites P1/Qg region, which is dead now)
    gated_norm_kernel<<<dim3(MT, NH), 256, 0, stream>>>(OB, P2, nw, ONB);

    // output projection
    transpose_cvt_kernel<<<dim3(VAL_DIM / 64, HID / 64), 256, 0, stream>>>(w_o, wT, VAL_DIM, HID);
    gemm_bf16_kernel<<<dim3(HID / BN, MT / BM), 256, 0, stream>>>(ONB, wT, out, MT, HID, VAL_DIM);
}